// Round 1
// baseline (2665.279 us; speedup 1.0000x reference)
//
#include <hip/hip_runtime.h>
#include <math.h>

#define SLEN 512
#define NB   1024

typedef _Float16 h2_t __attribute__((ext_vector_type(2)));

union U32H2 { unsigned int u; h2_t h; };

static __device__ __forceinline__ float fdot2f(h2_t a, h2_t b, float c){
#if __has_builtin(__builtin_amdgcn_fdot2)
  return __builtin_amdgcn_fdot2(a, b, c, false);
#else
  return c + (float)a[0]*(float)b[0] + (float)a[1]*(float)b[1];
#endif
}
static __device__ __forceinline__ h2_t u2h(unsigned int u){ U32H2 x; x.u=u; return x.h; }
static __device__ __forceinline__ unsigned int packf2(float a, float b){
  U32H2 x; x.h[0]=(_Float16)a; x.h[1]=(_Float16)b; return x.u;
}
static __device__ __forceinline__ float sigm(float v){ return 1.0f/(1.0f+__expf(-v)); }
static __device__ __forceinline__ float gelu_exact(float v){
  return 0.5f*v*(1.0f+erff(v*0.7071067811865475f));
}

// ---------------------------------------------------------------------------
// Tables: a_gx[100][384], t_gx[4][384], a_y[100][128], t_y[4][128], w_y[384]
// gx = W_ih @ [x_enc(128), ae(32), te(16), y(1)] ; yW1 cols: [h(128), x_enc(128), ae(32), te(16)]
// ---------------------------------------------------------------------------
__global__ void k_tables(const float* __restrict__ W_ih, const float* __restrict__ yW1,
                         const float* __restrict__ a_emb, const float* __restrict__ t_emb,
                         float* __restrict__ agx, float* __restrict__ tgx,
                         float* __restrict__ ay, float* __restrict__ ty,
                         float* __restrict__ wy)
{
  const int v = blockIdx.x;
  const int o = threadIdx.x;           // 0..383
  if (v == 0) wy[o] = W_ih[o*177 + 176];
  if (v < 100) {
    float acc = 0.f;
    #pragma unroll
    for (int j=0;j<32;++j) acc += W_ih[o*177+128+j]*a_emb[v*32+j];
    agx[v*384+o] = acc;
    if (o < 128) {
      float a2 = 0.f;
      #pragma unroll
      for (int j=0;j<32;++j) a2 += yW1[o*304+256+j]*a_emb[v*32+j];
      ay[v*128+o] = a2;
    }
  } else {
    const int vt = v-100;
    float acc = 0.f;
    #pragma unroll
    for (int j=0;j<16;++j) acc += W_ih[o*177+160+j]*t_emb[vt*16+j];
    tgx[vt*384+o] = acc;
    if (o < 128) {
      float a2 = 0.f;
      #pragma unroll
      for (int j=0;j<16;++j) a2 += yW1[o*304+288+j]*t_emb[vt*16+j];
      ty[vt*128+o] = a2;
    }
  }
}

// ---------------------------------------------------------------------------
// Per-sample precompute: x_enc -> h0[b,128], x_gx[b,384] (+b_ih, +b_hh r/z), yx[b,128] (+yb1)
// ---------------------------------------------------------------------------
__global__ void k_sample(const float* __restrict__ x, const float* __restrict__ xW, const float* __restrict__ xb,
                         const float* __restrict__ h0W, const float* __restrict__ h0b,
                         const float* __restrict__ W_ih, const float* __restrict__ b_ih, const float* __restrict__ b_hh,
                         const float* __restrict__ yW1, const float* __restrict__ yb1,
                         float* __restrict__ w_h0, float* __restrict__ w_xgx, float* __restrict__ w_yx)
{
  const int b = blockIdx.x, tid = threadIdx.x;   // 384 threads
  __shared__ float sx[128];
  __shared__ float sxe[128];
  if (tid < 128) sx[tid] = x[b*128+tid];
  __syncthreads();
  if (tid < 128) {
    float acc = xb[tid];
    #pragma unroll 8
    for (int j=0;j<128;++j) acc += xW[tid*128+j]*sx[j];
    sxe[tid] = acc;
  }
  __syncthreads();
  {
    const int o = tid;
    float acc = b_ih[o] + (o < 256 ? b_hh[o] : 0.f);   // fold b_hh for r,z only (n-part is scaled by r)
    #pragma unroll 8
    for (int j=0;j<128;++j) acc += W_ih[o*177+j]*sxe[j];
    w_xgx[b*384+o] = acc;
  }
  if (tid < 128) {
    float acc = h0b[tid];
    #pragma unroll 8
    for (int j=0;j<128;++j) acc += h0W[tid*128+j]*sxe[j];
    w_h0[b*128+tid] = tanhf(acc);
    float a2 = yb1[tid];
    #pragma unroll 8
    for (int j=0;j<128;++j) a2 += yW1[tid*304+128+j]*sxe[j];
    w_yx[b*128+tid] = a2;
  }
}

// ---------------------------------------------------------------------------
// Recurrence: 512 WGs x 384 thr, 2 samples/WG. Thread o holds W_hh row o (f16x2 regs).
// Per step: gh = W_hh@h via v_dot2 (h broadcast from LDS); epilogue computes gates in fp32.
// Writes pre-update h to h_seq (this IS output 2 and the heads' input).
// ---------------------------------------------------------------------------
__global__ __launch_bounds__(384,3) void k_recur(
  const float* __restrict__ W_hh, const float* __restrict__ b_hh,
  const int* __restrict__ a, const int* __restrict__ t,
  const float* __restrict__ y, const float* __restrict__ mask,
  const float* __restrict__ w_h0, const float* __restrict__ w_xgx,
  const float* __restrict__ w_agx, const float* __restrict__ w_tgx,
  const float* __restrict__ w_wy,
  float* __restrict__ o_h)
{
  const int tid = threadIdx.x;
  const int b0 = blockIdx.x*2;
  __shared__ __align__(16) unsigned int s_h16[2][64];  // h packed f16x2
  __shared__ float s_h32[2][128];                      // h master copy fp32
  __shared__ float s_gh[384][2];                       // gh results (stride 2 -> 2-way = free)
  __shared__ float s_wy[384];
  __shared__ float s_bhn[128];
  __shared__ int   s_ai[2], s_ti[2];
  __shared__ float s_yv[2], s_mv[2];

  // register-stationary W_hh row (64 packed half2 = 64 VGPRs)
  h2_t w[64];
  {
    const float* wr = W_hh + tid*128;
    #pragma unroll
    for (int k=0;k<64;++k) w[k] = u2h(packf2(wr[2*k], wr[2*k+1]));
  }
  s_wy[tid] = w_wy[tid];
  if (tid < 128) s_bhn[tid] = b_hh[256+tid];
  if (tid < 256) { int smp=tid>>7, i=tid&127; s_h32[smp][i] = w_h0[(b0+smp)*128+i]; }
  __syncthreads();
  if (tid < 128) { int smp=tid>>6, k2=tid&63;
    s_h16[smp][k2] = packf2(s_h32[smp][2*k2], s_h32[smp][2*k2+1]); }
  __syncthreads();

  for (int s=0; s<SLEN; ++s) {
    // Phase A: gh dots (all 384 threads), 4 independent accumulator chains
    float a0a=0.f, a0b=0.f, a1a=0.f, a1b=0.f;
    const uint4* p0 = (const uint4*)&s_h16[0][0];
    const uint4* p1 = (const uint4*)&s_h16[1][0];
    #pragma unroll
    for (int q=0;q<16;++q) {
      uint4 hA = p0[q], hB = p1[q];
      a0a = fdot2f(w[4*q+0], u2h(hA.x), a0a);
      a0b = fdot2f(w[4*q+1], u2h(hA.y), a0b);
      a0a = fdot2f(w[4*q+2], u2h(hA.z), a0a);
      a0b = fdot2f(w[4*q+3], u2h(hA.w), a0b);
      a1a = fdot2f(w[4*q+0], u2h(hB.x), a1a);
      a1b = fdot2f(w[4*q+1], u2h(hB.y), a1b);
      a1a = fdot2f(w[4*q+2], u2h(hB.z), a1a);
      a1b = fdot2f(w[4*q+3], u2h(hB.w), a1b);
    }
    s_gh[tid][0] = a0a + a0b;
    s_gh[tid][1] = a1a + a1b;
    if (tid >= 376 && tid < 378) {   // per-step scalars
      int smp = tid-376; int idx = (b0+smp)*SLEN + s;
      s_ai[smp]=a[idx]; s_ti[smp]=t[idx]; s_yv[smp]=y[idx]; s_mv[smp]=mask[idx];
    }
    __syncthreads();
    // Phase B: gates + h update + h_seq write (pre-update h)
    if (tid < 256) {
      const int smp = tid>>7, i = tid&127, b = b0+smp;
      const float ghr = s_gh[i][smp];
      const float ghz = s_gh[i+128][smp];
      const float ghn = s_gh[i+256][smp] + s_bhn[i];
      const int av = s_ai[smp], tv = s_ti[smp];
      const float yv = s_yv[smp], mv = s_mv[smp];
      const float* xg = w_xgx + b*384;
      const float* ag = w_agx + av*384;
      const float* tg = w_tgx + tv*384;
      const float gxr = xg[i]     + ag[i]     + tg[i]     + yv*s_wy[i];
      const float gxz = xg[i+128] + ag[i+128] + tg[i+128] + yv*s_wy[i+128];
      const float gxn = xg[i+256] + ag[i+256] + tg[i+256] + yv*s_wy[i+256];
      const float r = sigm(gxr + ghr);
      const float z = sigm(gxz + ghz);
      const float n = tanhf(gxn + r*ghn);
      const float hold = s_h32[smp][i];
      o_h[((size_t)b*SLEN + s)*128 + i] = hold;
      const float hn = (1.f - z)*n + z*hold;
      s_h32[smp][i] = mv*hn + (1.f - mv)*hold;
    }
    __syncthreads();
    // Phase C: repack h to f16x2
    if (tid < 128) { int smp=tid>>6, k2=tid&63;
      s_h16[smp][k2] = packf2(s_h32[smp][2*k2], s_h32[smp][2*k2+1]); }
    __syncthreads();
  }
}

// ---------------------------------------------------------------------------
// Heads: per (b,s): t_logits = gelu(h@tW1^T+tb1)@tW2^T+tb2 ; y = dot(gelu(h@yW1h^T+ypre), yW2)+yb2
// 8192 WGs x 256 thr, 64 pairs/WG, register-stationary tW1/yW1h rows, f16 dot2.
// ---------------------------------------------------------------------------
__global__ __launch_bounds__(256,2) void k_heads(
  const float* __restrict__ tW1, const float* __restrict__ tb1,
  const float* __restrict__ tW2, const float* __restrict__ tb2,
  const float* __restrict__ yW1, const float* __restrict__ yW2, const float* __restrict__ yb2,
  const int* __restrict__ a, const int* __restrict__ t,
  const float* __restrict__ w_yx, const float* __restrict__ w_ay, const float* __restrict__ w_ty,
  const float* __restrict__ h_in,
  float* __restrict__ o_y, float* __restrict__ o_t)
{
  const int tid = threadIdx.x;
  const int k = tid & 127, pr = tid >> 7;
  __shared__ unsigned int s_stage[128*65];             // padded: bank-conflict-free row reads
  __shared__ __align__(16) unsigned int s_h[2][64];
  __shared__ float s_g1[2][128];
  __shared__ float s_g2[2][128];
  __shared__ float s_tw2[512];
  __shared__ float s_yw2[128];

  // stage tW1 -> regs
  for (int idx=tid; idx<8192; idx+=256) { int row=idx>>6, c=idx&63;
    s_stage[row*65+c] = packf2(tW1[row*128+2*c], tW1[row*128+2*c+1]); }
  s_tw2[tid] = tW2[tid]; s_tw2[tid+256] = tW2[tid+256];
  if (tid < 128) s_yw2[tid] = yW2[tid];
  __syncthreads();
  h2_t w1[64];
  #pragma unroll
  for (int c=0;c<64;++c) w1[c] = u2h(s_stage[k*65+c]);
  __syncthreads();
  // stage yW1 h-columns -> regs
  for (int idx=tid; idx<8192; idx+=256) { int row=idx>>6, c=idx&63;
    s_stage[row*65+c] = packf2(yW1[row*304+2*c], yW1[row*304+2*c+1]); }
  __syncthreads();
  h2_t w2[64];
  #pragma unroll
  for (int c=0;c<64;++c) w2[c] = u2h(s_stage[k*65+c]);

  const float tb1r = tb1[k];
  const size_t p0 = (size_t)blockIdx.x * 64;

  for (int pass=0; pass<32; ++pass) {
    __syncthreads();                       // protect s_h / s_g reuse
    if (tid < 128) {                       // stage h (2 pairs) as f16x2
      const int pr2 = tid>>6, k2 = tid&63;
      const size_t pp = p0 + pass*2 + pr2;
      const float* hp = h_in + pp*128;
      s_h[pr2][k2] = packf2(hp[2*k2], hp[2*k2+1]);
    }
    __syncthreads();
    const size_t p = p0 + pass*2 + pr;
    const int b = (int)(p >> 9);
    const int av = a[p], tv = t[p];
    const float ypre = w_yx[b*128+k] + w_ay[av*128+k] + w_ty[tv*128+k];
    float aT0 = tb1r, aT1 = 0.f, aY0 = ypre, aY1 = 0.f;
    const uint4* hp4 = (const uint4*)&s_h[pr][0];
    #pragma unroll
    for (int q=0;q<16;++q) {
      uint4 hh = hp4[q];
      aT0 = fdot2f(w1[4*q+0], u2h(hh.x), aT0);
      aT1 = fdot2f(w1[4*q+1], u2h(hh.y), aT1);
      aT0 = fdot2f(w1[4*q+2], u2h(hh.z), aT0);
      aT1 = fdot2f(w1[4*q+3], u2h(hh.w), aT1);
      aY0 = fdot2f(w2[4*q+0], u2h(hh.x), aY0);
      aY1 = fdot2f(w2[4*q+1], u2h(hh.y), aY1);
      aY0 = fdot2f(w2[4*q+2], u2h(hh.z), aY0);
      aY1 = fdot2f(w2[4*q+3], u2h(hh.w), aY1);
    }
    s_g1[pr][k] = gelu_exact(aT0 + aT1);
    s_g2[pr][k] = gelu_exact(aY0 + aY1);
    __syncthreads();
    const int wv = tid>>6, l = tid&63;     // wave wv reduces pair wv (waves 0,1)
    if (wv < 2) {
      const float* g1p = s_g1[wv];
      const float* g2p = s_g2[wv];
      float q0 = g1p[l]*s_tw2[l]     + g1p[l+64]*s_tw2[l+64];
      float q1 = g1p[l]*s_tw2[128+l] + g1p[l+64]*s_tw2[192+l];
      float q2 = g1p[l]*s_tw2[256+l] + g1p[l+64]*s_tw2[320+l];
      float q3 = g1p[l]*s_tw2[384+l] + g1p[l+64]*s_tw2[448+l];
      float qy = g2p[l]*s_yw2[l]     + g2p[l+64]*s_yw2[l+64];
      #pragma unroll
      for (int off=32; off>=1; off>>=1) {
        q0 += __shfl_xor(q0, off);
        q1 += __shfl_xor(q1, off);
        q2 += __shfl_xor(q2, off);
        q3 += __shfl_xor(q3, off);
        qy += __shfl_xor(qy, off);
      }
      if (l == 0) {
        const size_t pp = p0 + pass*2 + wv;
        o_t[pp*4+0] = q0 + tb2[0];
        o_t[pp*4+1] = q1 + tb2[1];
        o_t[pp*4+2] = q2 + tb2[2];
        o_t[pp*4+3] = q3 + tb2[3];
        o_y[pp]     = qy + yb2[0];
      }
    }
  }
}

// ---------------------------------------------------------------------------
extern "C" void kernel_launch(void* const* d_in, const int* in_sizes, int n_in,
                              void* d_out, int out_size, void* d_ws, size_t ws_size,
                              hipStream_t stream) {
  (void)in_sizes; (void)n_in; (void)out_size; (void)ws_size;
  const float* x     = (const float*)d_in[0];
  const int*   a     = (const int*)  d_in[1];
  const int*   tt    = (const int*)  d_in[2];
  const float* y     = (const float*)d_in[3];
  const float* mask  = (const float*)d_in[4];
  const float* xW    = (const float*)d_in[5];
  const float* xb    = (const float*)d_in[6];
  const float* a_emb = (const float*)d_in[7];
  const float* t_emb = (const float*)d_in[8];
  const float* W_ih  = (const float*)d_in[9];
  const float* b_ih  = (const float*)d_in[10];
  const float* W_hh  = (const float*)d_in[11];
  const float* b_hh  = (const float*)d_in[12];
  const float* h0W   = (const float*)d_in[13];
  const float* h0b   = (const float*)d_in[14];
  const float* tW1   = (const float*)d_in[15];
  const float* tb1   = (const float*)d_in[16];
  const float* tW2   = (const float*)d_in[17];
  const float* tb2   = (const float*)d_in[18];
  const float* yW1   = (const float*)d_in[19];
  const float* yb1   = (const float*)d_in[20];
  const float* yW2   = (const float*)d_in[21];
  const float* yb2   = (const float*)d_in[22];

  float* o_y = (float*)d_out;                  // [B,S,1]   524288
  float* o_t = o_y + 524288;                   // [B,S,4]   2097152
  float* o_h = o_y + 2621440;                  // [B,S,128] 67108864

  float* ws    = (float*)d_ws;
  float* w_h0  = ws;                 // 131072
  float* w_xgx = ws + 131072;        // 393216
  float* w_yx  = ws + 524288;        // 131072
  float* w_agx = ws + 655360;        // 38400
  float* w_tgx = ws + 693760;        // 1536
  float* w_ay  = ws + 695296;        // 12800
  float* w_ty  = ws + 708096;        // 512
  float* w_wy  = ws + 708608;        // 384

  k_tables<<<104, 384, 0, stream>>>(W_ih, yW1, a_emb, t_emb, w_agx, w_tgx, w_ay, w_ty, w_wy);
  k_sample<<<1024, 384, 0, stream>>>(x, xW, xb, h0W, h0b, W_ih, b_ih, b_hh, yW1, yb1,
                                     w_h0, w_xgx, w_yx);
  k_recur<<<512, 384, 0, stream>>>(W_hh, b_hh, a, tt, y, mask, w_h0, w_xgx, w_agx, w_tgx, w_wy, o_h);
  k_heads<<<8192, 256, 0, stream>>>(tW1, tb1, tW2, tb2, yW1, yW2, yb2, a, tt,
                                    w_yx, w_ay, w_ty, o_h, o_y, o_t);
}

// Round 3
// 1879.304 us; speedup vs baseline: 1.4182x; 1.4182x over previous
//
#include <hip/hip_runtime.h>
#include <math.h>

#define SLEN 512

typedef _Float16 half8 __attribute__((ext_vector_type(8)));
typedef _Float16 half2v __attribute__((ext_vector_type(2)));
typedef __fp16 fp16x2 __attribute__((ext_vector_type(2)));
typedef float f32x4 __attribute__((ext_vector_type(4)));
typedef unsigned int uint;

union U4H8 { uint4 u; half8 h; };
union UH2 { uint u; half2v v; fp16x2 p; };

static __device__ __forceinline__ uint packh2(float a, float b){
  UH2 x; x.p = __builtin_amdgcn_cvt_pkrtz(a, b); return x.u;
}
static __device__ __forceinline__ float loh(uint u){ UH2 x; x.u=u; return (float)x.v[0]; }
static __device__ __forceinline__ float hih(uint u){ UH2 x; x.u=u; return (float)x.v[1]; }
static __device__ __forceinline__ half8 ld_h8(const uint* p){
  U4H8 x; x.u = *(const uint4*)p; return x.h;
}
static __device__ __forceinline__ float rcpf(float x){ return __builtin_amdgcn_rcpf(x); }
static __device__ __forceinline__ float sigm(float v){ return rcpf(1.0f+__expf(-v)); }
static __device__ __forceinline__ float tanh_f(float v){ return 1.0f - 2.0f*rcpf(__expf(2.0f*v)+1.0f); }
static __device__ __forceinline__ float gelu_exact(float v){
  return 0.5f*v*(1.0f+erff(v*0.7071067811865475f));
}
#define MFMA(a,b,c) __builtin_amdgcn_mfma_f32_16x16x32_f16((a),(b),(c),0,0,0)

// ---------------------------------------------------------------------------
// Per-sample precompute: x_enc -> h0[b,128], x_gx[b,384] (+b_ih, +b_hh r/z), yx[b,128] (+yb1)
// ---------------------------------------------------------------------------
__global__ void k_sample(const float* __restrict__ x, const float* __restrict__ xW, const float* __restrict__ xb,
                         const float* __restrict__ h0W, const float* __restrict__ h0b,
                         const float* __restrict__ W_ih, const float* __restrict__ b_ih, const float* __restrict__ b_hh,
                         const float* __restrict__ yW1, const float* __restrict__ yb1,
                         float* __restrict__ w_h0, float* __restrict__ w_xgx, float* __restrict__ w_yx)
{
  const int b = blockIdx.x, tid = threadIdx.x;   // 384 threads
  __shared__ float sx[128];
  __shared__ float sxe[128];
  if (tid < 128) sx[tid] = x[b*128+tid];
  __syncthreads();
  if (tid < 128) {
    float acc = xb[tid];
    #pragma unroll 8
    for (int j=0;j<128;++j) acc += xW[tid*128+j]*sx[j];
    sxe[tid] = acc;
  }
  __syncthreads();
  {
    const int o = tid;
    float acc = b_ih[o] + (o < 256 ? b_hh[o] : 0.f);   // fold b_hh for r,z only
    #pragma unroll 8
    for (int j=0;j<128;++j) acc += W_ih[o*177+j]*sxe[j];
    w_xgx[b*384+o] = acc;
  }
  if (tid < 128) {
    float acc = h0b[tid];
    #pragma unroll 8
    for (int j=0;j<128;++j) acc += h0W[tid*128+j]*sxe[j];
    w_h0[b*128+tid] = tanhf(acc);
    float a2 = yb1[tid];
    #pragma unroll 8
    for (int j=0;j<128;++j) a2 += yW1[tid*304+128+j]*sxe[j];
    w_yx[b*128+tid] = a2;
  }
}

// ---------------------------------------------------------------------------
// MFMA recurrence. 64 WGs x 384 thr (6 waves), 16 samples per WG.
// waves: 0,1 = r-gate (row halves), 2,3 = z, 4,5 = n.
// Per wave: W_hh rows + W_ih[ae|te|y] tail as stationary A-frags (4 row-tiles x 6 k-tiles).
// h: LDS f16 [sample][k], stride 68 uints; read as B-frags.
// ---------------------------------------------------------------------------
__global__ __launch_bounds__(384,1) void k_recur(
  const float* __restrict__ W_hh, const float* __restrict__ W_ih, const float* __restrict__ b_hh,
  const int* __restrict__ a, const int* __restrict__ tt,
  const float* __restrict__ yy, const float* __restrict__ mask,
  const float* __restrict__ w_h0, const float* __restrict__ w_xgx,
  const float* __restrict__ a_emb, const float* __restrict__ t_emb,
  float* __restrict__ o_h)
{
  const int tid = threadIdx.x;
  const int wv = tid>>6, lane = tid&63, q = lane>>4, c = lane&15;
  const int g = wv>>1, H = wv&1;       // gate 0=r,1=z,2=n ; row half
  const int b0 = blockIdx.x*16;
  const int rowbase = g*128 + H*64;

  __shared__ __align__(16) uint s_h[2][16*68];     // h f16 [sample][k/2], pad
  __shared__ __align__(16) uint s_ext[2][16*36];   // [ae|te|y|0] f16 per sample
  __shared__ __align__(16) uint s_rz[2][1024];     // r-hat, z-hat f16 pairs
  __shared__ __align__(16) uint s_chunk[2][1024];  // [arr(a,t,y,m)][sample][16 steps]
  __shared__ __align__(16) uint s_al[1600];        // a_emb packed f16 [100][16]
  __shared__ __align__(16) uint s_te[32];          // t_emb packed f16 [4][8]

  // ---- stationary weight A-frags: wf[t4*6+kt]
  half8 wf[24];
  #pragma unroll
  for (int t4=0;t4<4;++t4) {
    const int row = rowbase + t4*16 + c;
    #pragma unroll
    for (int kt=0;kt<4;++kt) {
      const float4* wp = (const float4*)(W_hh + row*128 + kt*32 + q*8);
      float4 v0 = wp[0], v1 = wp[1];
      half8 hv;
      hv[0]=(_Float16)v0.x; hv[1]=(_Float16)v0.y; hv[2]=(_Float16)v0.z; hv[3]=(_Float16)v0.w;
      hv[4]=(_Float16)v1.x; hv[5]=(_Float16)v1.y; hv[6]=(_Float16)v1.z; hv[7]=(_Float16)v1.w;
      wf[t4*6+kt] = hv;
    }
    #pragma unroll
    for (int kt=4;kt<6;++kt) {
      half8 hv;
      #pragma unroll
      for (int j=0;j<8;++j) {
        int k2 = (kt-4)*32 + q*8 + j;
        float v = (k2 < 49) ? W_ih[row*177 + 128 + k2] : 0.f;
        hv[j] = (_Float16)v;
      }
      wf[t4*6+kt] = hv;
    }
  }
  // xg init (C-layout slots)
  f32x4 xg[4];
  #pragma unroll
  for (int t4=0;t4<4;++t4)
    #pragma unroll
    for (int r=0;r<4;++r)
      xg[t4][r] = w_xgx[(b0+c)*384 + rowbase + t4*16 + q*4 + r];
  // n-wave state
  f32x4 bhh[4]; float hm[16];
  if (g==2) {
    #pragma unroll
    for (int t4=0;t4<4;++t4)
      #pragma unroll
      for (int r=0;r<4;++r) {
        bhh[t4][r] = b_hh[256 + H*64 + t4*16 + q*4 + r];
        hm[t4*4+r] = w_h0[(b0+c)*128 + H*64 + t4*16 + q*4 + r];
      }
  }
  // stage embedding tables (packed f16)
  for (int d = tid; d < 1600; d += 384) {
    int row = d>>4, col = d&15;
    s_al[d] = packh2(a_emb[row*32+2*col], a_emb[row*32+2*col+1]);
  }
  if (tid < 32) {
    int row = tid>>3, col = tid&7;
    s_te[tid] = packh2(t_emb[row*16+2*col], t_emb[row*16+2*col+1]);
  }
  // chunk 0 (wave 0): arr q: 0=a,1=t,2=y,3=mask ; 16 steps per sample
  uint4 cr0, cr1, cr2, cr3;
  if (wv==0) {
    const uint* bp = (q==0) ? (const uint*)a : (q==1) ? (const uint*)tt
                   : (q==2) ? (const uint*)yy : (const uint*)mask;
    const uint4* p = (const uint4*)(bp + (size_t)(b0+c)*512);
    cr0=p[0]; cr1=p[1]; cr2=p[2]; cr3=p[3];
    uint4* dst = (uint4*)&s_chunk[0][q*256 + c*16];
    dst[0]=cr0; dst[1]=cr1; dst[2]=cr2; dst[3]=cr3;
  }
  // h0 -> s_h[0]
  if (g==2) {
    #pragma unroll
    for (int t4=0;t4<4;++t4) {
      int base = c*68 + H*32 + t4*8 + q*2;
      s_h[0][base]   = packh2(hm[t4*4+0], hm[t4*4+1]);
      s_h[0][base+1] = packh2(hm[t4*4+2], hm[t4*4+3]);
    }
  }
  __syncthreads();
  // ext for step 0 (r-waves)
  if (g==0) {
    int av = (int)s_chunk[0][c*16];
    int tv = (int)s_chunk[0][256 + c*16];
    uint yu = s_chunk[0][512 + c*16];
    float yv = __uint_as_float(yu);
    #pragma unroll
    for (int i=0;i<4;++i) {
      int d = H*16 + q*4 + i;
      uint u;
      if (d < 16) u = s_al[av*16 + d];
      else if (d < 24) u = s_te[tv*8 + (d-16)];
      else if (d == 24) u = packh2(yv, 0.f);
      else u = 0u;
      s_ext[0][c*36 + d] = u;
    }
  }
  __syncthreads();

  f32x4 acc[4], acc2[4];   // r/z: acc=gates ; n: acc=acc_h, acc2=acc_x

  for (int s=0; s<SLEN; ++s) {
    const int pb = s&1;
    // ---- B-frags
    half8 hb[4], eb[2];
    #pragma unroll
    for (int kt=0;kt<4;++kt) hb[kt] = ld_h8(&s_h[pb][c*68 + kt*16 + q*4]);
    #pragma unroll
    for (int e=0;e<2;++e)    eb[e]  = ld_h8(&s_ext[pb][c*36 + e*16 + q*4]);

    if (g < 2) {
      // z-waves: store o_h for step s-1 (buffer (s-1)&1 still stable pre-B1)
      if (g==1 && s>0) {
        const int ob = (s-1)&1;
        const int smp = H*8 + (lane>>3), ch = lane&7;
        const uint* hp = &s_h[ob][smp*68 + ch*8];
        float* op = o_h + ((size_t)(b0+smp)*SLEN + (s-1))*128 + ch*16;
        #pragma unroll
        for (int i2=0;i2<2;++i2) {
          uint4 u = *(const uint4*)(hp + i2*4);
          float4 f0 = make_float4(loh(u.x), hih(u.x), loh(u.y), hih(u.y));
          float4 f1 = make_float4(loh(u.z), hih(u.z), loh(u.w), hih(u.w));
          *(float4*)(op + i2*8)     = f0;
          *(float4*)(op + i2*8 + 4) = f1;
        }
      }
      #pragma unroll
      for (int t4=0;t4<4;++t4) acc[t4] = xg[t4];
      #pragma unroll
      for (int kt=0;kt<6;++kt) {
        half8 bsel = (kt<4) ? hb[kt] : eb[kt-4];
        #pragma unroll
        for (int t4=0;t4<4;++t4) acc[t4] = MFMA(wf[t4*6+kt], bsel, acc[t4]);
      }
      #pragma unroll
      for (int t4=0;t4<4;++t4)
        #pragma unroll
        for (int pr=0;pr<2;++pr) {
          float s0 = sigm(acc[t4][2*pr]), s1 = sigm(acc[t4][2*pr+1]);
          s_rz[g][(((H*4+t4)*2+pr)*4+q)*16 + c] = packh2(s0, s1);
        }
      // chunk prefetch (wave 0)
      if (wv==0) {
        if ((s&15)==8 && s<490) {
          const int s0n = ((s>>4)+1)*16;
          const uint* bp = (q==0) ? (const uint*)a : (q==1) ? (const uint*)tt
                         : (q==2) ? (const uint*)yy : (const uint*)mask;
          const uint4* p = (const uint4*)(bp + (size_t)(b0+c)*512 + s0n);
          cr0=p[0]; cr1=p[1]; cr2=p[2]; cr3=p[3];
        }
        if ((s&15)==9 && s<491) {
          uint4* dst = (uint4*)&s_chunk[((s>>4)+1)&1][q*256 + c*16];
          dst[0]=cr0; dst[1]=cr1; dst[2]=cr2; dst[3]=cr3;
        }
      }
    } else {
      #pragma unroll
      for (int t4=0;t4<4;++t4) { acc[t4] = bhh[t4]; acc2[t4] = xg[t4]; }
      #pragma unroll
      for (int kt=0;kt<4;++kt)
        #pragma unroll
        for (int t4=0;t4<4;++t4) acc[t4] = MFMA(wf[t4*6+kt], hb[kt], acc[t4]);
      #pragma unroll
      for (int kt=4;kt<6;++kt)
        #pragma unroll
        for (int t4=0;t4<4;++t4) acc2[t4] = MFMA(wf[t4*6+kt], eb[kt-4], acc2[t4]);
    }
    __syncthreads();   // B1
    if (g==2) {
      const float mval = __uint_as_float(s_chunk[(s>>4)&1][768 + c*16 + (s&15)]);
      #pragma unroll
      for (int t4=0;t4<4;++t4)
        #pragma unroll
        for (int pr=0;pr<2;++pr) {
          const int slot = (((H*4+t4)*2+pr)*4+q)*16 + c;
          uint ru = s_rz[0][slot], zu = s_rz[1][slot];
          const int i0 = t4*4 + 2*pr;
          float n0 = tanh_f(acc2[t4][2*pr]   + loh(ru)*acc[t4][2*pr]);
          float n1 = tanh_f(acc2[t4][2*pr+1] + hih(ru)*acc[t4][2*pr+1]);
          float h0o = hm[i0], h1o = hm[i0+1];
          float hn0 = n0 + loh(zu)*(h0o - n0);
          float hn1 = n1 + hih(zu)*(h1o - n1);
          hm[i0]   = h0o + mval*(hn0 - h0o);
          hm[i0+1] = h1o + mval*(hn1 - h1o);
        }
      const int nb = (s+1)&1;
      #pragma unroll
      for (int t4=0;t4<4;++t4) {
        int base = c*68 + H*32 + t4*8 + q*2;
        s_h[nb][base]   = packh2(hm[t4*4+0], hm[t4*4+1]);
        s_h[nb][base+1] = packh2(hm[t4*4+2], hm[t4*4+3]);
      }
    } else if (g==0 && s < SLEN-1) {
      const int sn = s+1;
      const int par2 = (sn>>4)&1, st = sn&15;
      int av = (int)s_chunk[par2][c*16 + st];
      int tv = (int)s_chunk[par2][256 + c*16 + st];
      float yv = __uint_as_float(s_chunk[par2][512 + c*16 + st]);
      #pragma unroll
      for (int i=0;i<4;++i) {
        int d = H*16 + q*4 + i;
        uint u;
        if (d < 16) u = s_al[av*16 + d];
        else if (d < 24) u = s_te[tv*8 + (d-16)];
        else if (d == 24) u = packh2(yv, 0.f);
        else u = 0u;
        s_ext[(s+1)&1][c*36 + d] = u;
      }
    }
    __syncthreads();   // B2
  }
  // epilogue: o_h for s=511
  if (g==1) {
    const int ob = (SLEN-1)&1;
    const int smp = H*8 + (lane>>3), ch = lane&7;
    const uint* hp = &s_h[ob][smp*68 + ch*8];
    float* op = o_h + ((size_t)(b0+smp)*SLEN + (SLEN-1))*128 + ch*16;
    #pragma unroll
    for (int i2=0;i2<2;++i2) {
      uint4 u = *(const uint4*)(hp + i2*4);
      float4 f0 = make_float4(loh(u.x), hih(u.x), loh(u.y), hih(u.y));
      float4 f1 = make_float4(loh(u.z), hih(u.z), loh(u.w), hih(u.w));
      *(float4*)(op + i2*8)     = f0;
      *(float4*)(op + i2*8 + 4) = f1;
    }
  }
}

// ---------------------------------------------------------------------------
// MFMA heads. 8192 WGs x 256 thr, 64 pairs/WG (4 tiles of 16).
// waves 0,1 = t-head; 2,3 = y-head. D1[unit][pair] = W . h^T (+ext for y),
// gelu, LDS round-trip, MFMA2 vs tW2 / yW2.
// ---------------------------------------------------------------------------
__global__ __launch_bounds__(256,1) void k_heads(
  const float* __restrict__ tW1, const float* __restrict__ tb1,
  const float* __restrict__ tW2, const float* __restrict__ tb2,
  const float* __restrict__ yW1, const float* __restrict__ yW2, const float* __restrict__ yb2,
  const int* __restrict__ a, const int* __restrict__ tt,
  const float* __restrict__ w_yx,
  const float* __restrict__ a_emb, const float* __restrict__ t_emb,
  const float* __restrict__ h_in,
  float* __restrict__ o_y, float* __restrict__ o_t)
{
  const int tid = threadIdx.x;
  const int wv = tid>>6, lane = tid&63, q = lane>>4, c = lane&15;
  const bool isY = (wv >= 2);
  const int p0 = blockIdx.x*64;
  const int b = blockIdx.x>>3;

  __shared__ __align__(16) uint s_ht[64*68];
  __shared__ __align__(16) uint s_ex[64*36];
  __shared__ __align__(16) uint s_gb[4][16*68];
  __shared__ int s_av[64], s_tv[64];

  // ---- stationary weights
  half8 wf[24*2];   // [ut*6+kt] for ut 0..7 (only kt<4 for t-head; 6 for y)
  const float* W1 = isY ? yW1 : tW1;
  const int w1stride = isY ? 304 : 128;
  #pragma unroll
  for (int ut=0;ut<8;++ut) {
    const int unit = ut*16 + c;
    #pragma unroll
    for (int kt=0;kt<4;++kt) {
      const float4* wp = (const float4*)(W1 + unit*w1stride + kt*32 + q*8);
      float4 v0 = wp[0], v1 = wp[1];
      half8 hv;
      hv[0]=(_Float16)v0.x; hv[1]=(_Float16)v0.y; hv[2]=(_Float16)v0.z; hv[3]=(_Float16)v0.w;
      hv[4]=(_Float16)v1.x; hv[5]=(_Float16)v1.y; hv[6]=(_Float16)v1.z; hv[7]=(_Float16)v1.w;
      wf[ut*6+kt] = hv;
    }
    #pragma unroll
    for (int kt=4;kt<6;++kt) {
      half8 hv;
      #pragma unroll
      for (int j=0;j<8;++j) {
        int k2 = (kt-4)*32 + q*8 + j;
        float v = (isY && k2 < 48) ? yW1[unit*304 + 256 + k2] : 0.f;
        hv[j] = (_Float16)v;
      }
      wf[ut*6+kt] = hv;
    }
  }
  // MFMA2 A-frags
  half8 w2f[4];
  #pragma unroll
  for (int kt=0;kt<4;++kt) {
    half8 hv;
    #pragma unroll
    for (int j=0;j<8;++j) {
      float v = 0.f;
      if (!isY && c < 4) v = tW2[c*128 + kt*32 + q*8 + j];
      if ( isY && c == 0) v = yW2[kt*32 + q*8 + j];
      hv[j] = (_Float16)v;
    }
    w2f[kt] = hv;
  }
  // bias / pre-add regs (C-layout slots)
  f32x4 bsr[8];
  #pragma unroll
  for (int ut=0;ut<8;++ut)
    #pragma unroll
    for (int r=0;r<4;++r)
      bsr[ut][r] = isY ? w_yx[b*128 + ut*16 + q*4 + r] : tb1[ut*16 + q*4 + r];
  float tb2r[4]; float yb2s = yb2[0];
  #pragma unroll
  for (int r=0;r<4;++r) tb2r[r] = tb2[r];

  // ---- stage: indices, h-tile (f32 -> f16 padded), ext
  if (tid < 64) s_av[tid] = a[p0+tid];
  else if (tid < 128) s_tv[tid-64] = tt[p0+tid-64];
  {
    const int pair = tid>>2, seg = tid&3;
    const float4* hp = (const float4*)(h_in + (size_t)(p0+pair)*128 + seg*32);
    #pragma unroll
    for (int i=0;i<4;++i) {
      float4 v0 = hp[2*i], v1 = hp[2*i+1];
      uint4 u;
      u.x = packh2(v0.x, v0.y); u.y = packh2(v0.z, v0.w);
      u.z = packh2(v1.x, v1.y); u.w = packh2(v1.z, v1.w);
      *(uint4*)&s_ht[pair*68 + seg*16 + i*4] = u;
    }
  }
  __syncthreads();
  {
    const int pair = tid>>2, dg = (tid&3)*8;
    const int av = s_av[pair], tv = s_tv[pair];
    #pragma unroll
    for (int i=0;i<8;++i) {
      int d = dg + i;
      uint u = 0u;
      if (d < 16) u = packh2(a_emb[av*32+2*d], a_emb[av*32+2*d+1]);
      else if (d < 24) u = packh2(t_emb[tv*16+2*(d-16)], t_emb[tv*16+2*(d-16)+1]);
      s_ex[pair*36 + d] = u;
    }
  }
  __syncthreads();

  // ---- per-tile work
  #pragma unroll 1
  for (int T=0; T<2; ++T) {
    const int tile = (wv&1)*2 + T;
    half8 hb[4], eb[2];
    #pragma unroll
    for (int kt=0;kt<4;++kt) hb[kt] = ld_h8(&s_ht[(tile*16+c)*68 + kt*16 + q*4]);
    if (isY) {
      #pragma unroll
      for (int e=0;e<2;++e) eb[e] = ld_h8(&s_ex[(tile*16+c)*36 + e*16 + q*4]);
    }
    f32x4 acc[8];
    #pragma unroll
    for (int ut=0;ut<8;++ut) { acc[ut][0]=0.f; acc[ut][1]=0.f; acc[ut][2]=0.f; acc[ut][3]=0.f; }
    #pragma unroll
    for (int kt=0;kt<4;++kt)
      #pragma unroll
      for (int ut=0;ut<8;++ut) acc[ut] = MFMA(wf[ut*6+kt], hb[kt], acc[ut]);
    if (isY) {
      #pragma unroll
      for (int kt=4;kt<6;++kt)
        #pragma unroll
        for (int ut=0;ut<8;++ut) acc[ut] = MFMA(wf[ut*6+kt], eb[kt-4], acc[ut]);
    }
    // gelu + pack into per-wave gbuf [pair][unit]
    #pragma unroll
    for (int ut=0;ut<8;++ut)
      #pragma unroll
      for (int pr=0;pr<2;++pr) {
        float g0 = gelu_exact(acc[ut][2*pr]   + bsr[ut][2*pr]);
        float g1 = gelu_exact(acc[ut][2*pr+1] + bsr[ut][2*pr+1]);
        s_gb[wv][c*68 + 8*ut + 2*q + pr] = packh2(g0, g1);
      }
    // MFMA2
    f32x4 a2; a2[0]=0.f; a2[1]=0.f; a2[2]=0.f; a2[3]=0.f;
    #pragma unroll
    for (int kt=0;kt<4;++kt) {
      half8 gb = ld_h8(&s_gb[wv][c*68 + kt*16 + q*4]);
      a2 = MFMA(w2f[kt], gb, a2);
    }
    if (lane < 16) {
      const int p = p0 + tile*16 + c;
      if (!isY) {
        float4 o = make_float4(a2[0]+tb2r[0], a2[1]+tb2r[1], a2[2]+tb2r[2], a2[3]+tb2r[3]);
        *(float4*)&o_t[(size_t)p*4] = o;
      } else {
        o_y[p] = a2[0] + yb2s;
      }
    }
  }
}

// ---------------------------------------------------------------------------
extern "C" void kernel_launch(void* const* d_in, const int* in_sizes, int n_in,
                              void* d_out, int out_size, void* d_ws, size_t ws_size,
                              hipStream_t stream) {
  (void)in_sizes; (void)n_in; (void)out_size; (void)ws_size;
  const float* x     = (const float*)d_in[0];
  const int*   a     = (const int*)  d_in[1];
  const int*   tt    = (const int*)  d_in[2];
  const float* y     = (const float*)d_in[3];
  const float* mask  = (const float*)d_in[4];
  const float* xW    = (const float*)d_in[5];
  const float* xb    = (const float*)d_in[6];
  const float* a_emb = (const float*)d_in[7];
  const float* t_emb = (const float*)d_in[8];
  const float* W_ih  = (const float*)d_in[9];
  const float* b_ih  = (const float*)d_in[10];
  const float* W_hh  = (const float*)d_in[11];
  const float* b_hh  = (const float*)d_in[12];
  const float* h0W   = (const float*)d_in[13];
  const float* h0b   = (const float*)d_in[14];
  const float* tW1   = (const float*)d_in[15];
  const float* tb1   = (const float*)d_in[16];
  const float* tW2   = (const float*)d_in[17];
  const float* tb2   = (const float*)d_in[18];
  const float* yW1   = (const float*)d_in[19];
  const float* yb1   = (const float*)d_in[20];
  const float* yW2   = (const float*)d_in[21];
  const float* yb2   = (const float*)d_in[22];

  float* o_y = (float*)d_out;                  // [B,S,1]   524288
  float* o_t = o_y + 524288;                   // [B,S,4]   2097152
  float* o_h = o_y + 2621440;                  // [B,S,128] 67108864

  float* ws    = (float*)d_ws;
  float* w_h0  = ws;                 // 131072
  float* w_xgx = ws + 131072;        // 393216
  float* w_yx  = ws + 524288;        // 131072

  k_sample<<<1024, 384, 0, stream>>>(x, xW, xb, h0W, h0b, W_ih, b_ih, b_hh, yW1, yb1,
                                     w_h0, w_xgx, w_yx);
  k_recur<<<64, 384, 0, stream>>>(W_hh, W_ih, b_hh, a, tt, y, mask,
                                  w_h0, w_xgx, a_emb, t_emb, o_h);
  k_heads<<<8192, 256, 0, stream>>>(tW1, tb1, tW2, tb2, yW1, yW2, yb2, a, tt,
                                    w_yx, a_emb, t_emb, o_h, o_y, o_t);
}